// Round 1
// baseline (285.786 us; speedup 1.0000x reference)
//
#include <hip/hip_runtime.h>
#include <hip/hip_bf16.h>
#include <stdint.h>

#define NB 8192
#define ND 1024
#define SCALE 20.0f   // 1/TEMPERATURE

typedef __bf16 bf16x8 __attribute__((ext_vector_type(8)));
typedef float  f32x4  __attribute__((ext_vector_type(4)));

// ---------------- input-format detection (device-side, deterministic) -------
// relations: int32 or int64?  int64 -> all odd 32-bit words (high halves of
// values 0..127) are zero.  int32 -> odd words are random 0..127; P(all 128
// sampled odd words zero) = 128^-128.
// is_true: bool bytes (words <= 0x01010101, many > 1), int32 0/1 (all words
// in {0,1}), or f32 (words are 0 or 0x3F800000).
__device__ inline void detect_formats(const void* rel_raw, const void* ist_raw,
                                      int& rel64, int& bmode) {
  const unsigned int* r = (const unsigned int*)rel_raw;
  int is64 = 1;
  for (int i = 1; i < 256; i += 2) {
    if (r[i] != 0u) { is64 = 0; break; }
  }
  rel64 = is64;
  const unsigned int* t = (const unsigned int*)ist_raw;
  bool sawf = false, sawbig = false;
  for (int i = 0; i < 64; ++i) {
    unsigned int w = t[i];
    if (w == 0x3F800000u) sawf = true;
    else if (w > 1u) sawbig = true;
  }
  bmode = sawf ? 2 : (sawbig ? 1 : 0);
}

__device__ inline int decode_key(const void* rel_raw, const void* ist_raw,
                                 int rel64, int bmode, int i) {
  const int* r32 = (const int*)rel_raw;
  int r = rel64 ? r32[2 * i] : r32[i];
  int truth;
  if (bmode == 1)      truth = (((const unsigned char*)ist_raw)[i] != 0);
  else if (bmode == 2) truth = (((const float*)ist_raw)[i] != 0.0f);
  else                 truth = (((const int*)ist_raw)[i] != 0);
  return truth ? r : -1;
}

__device__ inline bf16x8 cvt8(const float4& a, const float4& b) {
  bf16x8 v;
  v[0] = (__bf16)a.x; v[1] = (__bf16)a.y; v[2] = (__bf16)a.z; v[3] = (__bf16)a.w;
  v[4] = (__bf16)b.x; v[5] = (__bf16)b.y; v[6] = (__bf16)b.z; v[7] = (__bf16)b.w;
  return v;
}

// ---------------- prep: f32->bf16 convert + zero accumulators + decode keys -
__global__ void prep_kernel(const float* __restrict__ emb,
                            const void* __restrict__ rel_raw,
                            const void* __restrict__ ist_raw,
                            __bf16* __restrict__ embB,
                            float* __restrict__ sum_exp,
                            float* __restrict__ numer,
                            int* __restrict__ key) {
  int tid = blockIdx.x * 256 + threadIdx.x;
  size_t base = (size_t)tid * 8;
  if (base < (size_t)NB * ND) {
    float4 a = *(const float4*)(emb + base);
    float4 b = *(const float4*)(emb + base + 4);
    *(bf16x8*)(embB + base) = cvt8(a, b);
  }
  if (tid < NB) { sum_exp[tid] = 0.f; numer[tid] = 0.f; }
  __shared__ int s_rel64, s_bmode;
  if (blockIdx.x < 32) {                 // block-uniform branch
    if (threadIdx.x == 0) {
      int a, b; detect_formats(rel_raw, ist_raw, a, b);
      s_rel64 = a; s_bmode = b;
    }
    __syncthreads();
    int i = blockIdx.x * 256 + threadIdx.x;   // < 8192
    key[i] = decode_key(rel_raw, ist_raw, s_rel64, s_bmode, i);
  }
}

// small-ws fallback prep (no bf16 buffer)
__global__ void prep_small_kernel(const void* __restrict__ rel_raw,
                                  const void* __restrict__ ist_raw,
                                  float* __restrict__ sum_exp,
                                  float* __restrict__ numer,
                                  int* __restrict__ key) {
  int i = blockIdx.x * 256 + threadIdx.x;     // 32 blocks -> 8192
  sum_exp[i] = 0.f; numer[i] = 0.f;
  __shared__ int s_rel64, s_bmode;
  if (threadIdx.x == 0) {
    int a, b; detect_formats(rel_raw, ist_raw, a, b);
    s_rel64 = a; s_bmode = b;
  }
  __syncthreads();
  key[i] = decode_key(rel_raw, ist_raw, s_rel64, s_bmode, i);
}

// ---------------- fused GEMM (E E^T) + exp + masked row sums ---------------
// 128x128 tile, BK=64, 4 waves in 2x2, each wave 64x64 = 4x4 frags of
// 16x16x32 bf16 MFMA.  Epilogue: e = exp(20*c); skip diagonal; sum_exp row
// sums + positive-pair (key match) numer sums via 16-lane shuffle reduce +
// one atomicAdd per fragment-row per wave.
template <bool F32STAGE>
__global__ __launch_bounds__(256, 2)
void gemm_fused_kernel(const __bf16* __restrict__ embB,
                       const float* __restrict__ embF,
                       const int* __restrict__ key,
                       float* __restrict__ sum_exp,
                       float* __restrict__ numer) {
  __shared__ __bf16 sA[128 * 64];
  __shared__ __bf16 sB[128 * 64];
  __shared__ int keyR[128], keyC[128];

  const int tid = threadIdx.x;
  const int wid = tid >> 6;
  const int l   = tid & 63;
  const int wr  = wid >> 1;     // wave row (0..1)
  const int wc  = wid & 1;      // wave col (0..1)
  const int rowBase = blockIdx.y * 128;
  const int colBase = blockIdx.x * 128;

  if (tid < 128) keyR[tid] = key[rowBase + tid];
  else           keyC[tid - 128] = key[colBase + tid - 128];

  f32x4 acc[4][4] = {};

  for (int k0 = 0; k0 < ND; k0 += 64) {
    __syncthreads();   // previous iter's LDS reads done
    if constexpr (!F32STAGE) {
#pragma unroll
      for (int c = 0; c < 4; ++c) {
        int seg = wid * 4 + c;            // 0..15, wave-uniform
        int row = seg * 8 + (l >> 3);     // 0..127
        int ko  = (l & 7) * 8;
        const __bf16* ga = embB + (size_t)(rowBase + row) * ND + k0 + ko;
        const __bf16* gb = embB + (size_t)(colBase + row) * ND + k0 + ko;
        __builtin_amdgcn_global_load_lds(
            (const __attribute__((address_space(1))) void*)ga,
            (__attribute__((address_space(3))) void*)&sA[seg * 512], 16, 0, 0);
        __builtin_amdgcn_global_load_lds(
            (const __attribute__((address_space(1))) void*)gb,
            (__attribute__((address_space(3))) void*)&sB[seg * 512], 16, 0, 0);
      }
    } else {
#pragma unroll
      for (int c = 0; c < 4; ++c) {
        int chunk = tid + c * 256;        // 0..1023
        int row = chunk >> 3;
        int ko  = (chunk & 7) * 8;
        const float* gfa = embF + (size_t)(rowBase + row) * ND + k0 + ko;
        const float* gfb = embF + (size_t)(colBase + row) * ND + k0 + ko;
        float4 a0 = *(const float4*)gfa;
        float4 a1 = *(const float4*)(gfa + 4);
        float4 b0 = *(const float4*)gfb;
        float4 b1 = *(const float4*)(gfb + 4);
        *(bf16x8*)&sA[row * 64 + ko] = cvt8(a0, a1);
        *(bf16x8*)&sB[row * 64 + ko] = cvt8(b0, b1);
      }
    }
    __syncthreads();

#pragma unroll
    for (int kk = 0; kk < 2; ++kk) {
      bf16x8 af[4], bfr[4];
#pragma unroll
      for (int m = 0; m < 4; ++m)
        af[m] = *(const bf16x8*)&sA[(wr * 64 + m * 16 + (l & 15)) * 64 + kk * 32 + (l >> 4) * 8];
#pragma unroll
      for (int n = 0; n < 4; ++n)
        bfr[n] = *(const bf16x8*)&sB[(wc * 64 + n * 16 + (l & 15)) * 64 + kk * 32 + (l >> 4) * 8];
#pragma unroll
      for (int m = 0; m < 4; ++m)
#pragma unroll
        for (int n = 0; n < 4; ++n)
          acc[m][n] = __builtin_amdgcn_mfma_f32_16x16x32_bf16(af[m], bfr[n], acc[m][n], 0, 0, 0);
    }
  }

  // epilogue: C/D layout col = lane&15, row = (lane>>4)*4 + reg
#pragma unroll
  for (int m = 0; m < 4; ++m) {
#pragma unroll
    for (int r4 = 0; r4 < 4; ++r4) {
      int li = wr * 64 + m * 16 + (l >> 4) * 4 + r4;
      int gi = rowBase + li;
      int krow = keyR[li];
      float se = 0.f, nu = 0.f;
#pragma unroll
      for (int n = 0; n < 4; ++n) {
        int lj = wc * 64 + n * 16 + (l & 15);
        int gj = colBase + lj;
        if (gi != gj) {
          float e = __expf(acc[m][n][r4] * SCALE);
          se += e;
          if (krow >= 0 && krow == keyC[lj]) nu += e;
        }
      }
#pragma unroll
      for (int off = 8; off; off >>= 1) {
        se += __shfl_xor(se, off, 16);
        nu += __shfl_xor(nu, off, 16);
      }
      if ((l & 15) == 0) {
        atomicAdd(&sum_exp[gi], se);
        if (nu != 0.f) atomicAdd(&numer[gi], nu);
      }
    }
  }
}

// ---------------- finalize: histogram -> has_pos, losses, reductions -------
__global__ void finalize_kernel(const float* __restrict__ sum_exp,
                                const float* __restrict__ numer,
                                const int* __restrict__ key,
                                float* __restrict__ out) {
  __shared__ int cnt[128];
  __shared__ float wsum[16];
  __shared__ int wcnt[16];
  int tid = threadIdx.x;      // 1024 threads
  if (tid < 128) cnt[tid] = 0;
  __syncthreads();
  for (int i = tid; i < NB; i += 1024) {
    int k = key[i];
    if (k >= 0) atomicAdd(&cnt[k], 1);
  }
  __syncthreads();
  float ls = 0.f; int np = 0;
  for (int i = tid; i < NB; i += 1024) {
    int k = key[i];
    if (k >= 0 && cnt[k] >= 2) {
      np++;
      ls += logf(sum_exp[i] + 1e-8f) - logf(numer[i]);
    }
  }
  for (int off = 32; off; off >>= 1) {
    ls += __shfl_down(ls, off, 64);
    np += __shfl_down(np, off, 64);
  }
  int w = tid >> 6;
  if ((tid & 63) == 0) { wsum[w] = ls; wcnt[w] = np; }
  __syncthreads();
  if (tid == 0) {
    float s = 0.f; int n = 0;
    for (int i = 0; i < 16; ++i) { s += wsum[i]; n += wcnt[i]; }
    out[0] = (n > 0) ? (s / (float)n) : 0.f;
    out[1] = (float)n;
  }
}

// ---------------------------------------------------------------------------
extern "C" void kernel_launch(void* const* d_in, const int* in_sizes, int n_in,
                              void* d_out, int out_size, void* d_ws, size_t ws_size,
                              hipStream_t stream) {
  const float* emb = (const float*)d_in[0];
  const void* rel  = d_in[1];
  const void* ist  = d_in[2];
  float* out = (float*)d_out;

  const size_t embBytes = (size_t)NB * ND * sizeof(__bf16);   // 16 MiB
  const size_t smallBytes = (size_t)NB * 4 * 3;               // 96 KiB

  char* ws = (char*)d_ws;
  if (ws_size >= embBytes + smallBytes) {
    __bf16* embB   = (__bf16*)ws;
    float* sum_exp = (float*)(ws + embBytes);
    float* numer   = sum_exp + NB;
    int*   key     = (int*)(numer + NB);
    prep_kernel<<<4096, 256, 0, stream>>>(emb, rel, ist, embB, sum_exp, numer, key);
    gemm_fused_kernel<false><<<dim3(64, 64), 256, 0, stream>>>(embB, nullptr, key, sum_exp, numer);
    finalize_kernel<<<1, 1024, 0, stream>>>(sum_exp, numer, key, out);
  } else {
    float* sum_exp = (float*)ws;
    float* numer   = sum_exp + NB;
    int*   key     = (int*)(numer + NB);
    prep_small_kernel<<<32, 256, 0, stream>>>(rel, ist, sum_exp, numer, key);
    gemm_fused_kernel<true><<<dim3(64, 64), 256, 0, stream>>>(nullptr, emb, key, sum_exp, numer);
    finalize_kernel<<<1, 1024, 0, stream>>>(sum_exp, numer, key, out);
  }
}

// Round 2
// 141.118 us; speedup vs baseline: 2.0252x; 2.0252x over previous
//
#include <hip/hip_runtime.h>
#include <hip/hip_bf16.h>
#include <stdint.h>

#define NB 8192
#define ND 1024
#define SCALE 20.0f   // 1/TEMPERATURE

typedef __bf16 bf16x8 __attribute__((ext_vector_type(8)));
typedef float  f32x4  __attribute__((ext_vector_type(4)));

// ---------------- input-format detection (device-side, deterministic) -------
__device__ inline void detect_formats(const void* rel_raw, const void* ist_raw,
                                      int& rel64, int& bmode) {
  const unsigned int* r = (const unsigned int*)rel_raw;
  int is64 = 1;
  for (int i = 1; i < 256; i += 2) {
    if (r[i] != 0u) { is64 = 0; break; }
  }
  rel64 = is64;
  const unsigned int* t = (const unsigned int*)ist_raw;
  bool sawf = false, sawbig = false;
  for (int i = 0; i < 64; ++i) {
    unsigned int w = t[i];
    if (w == 0x3F800000u) sawf = true;
    else if (w > 1u) sawbig = true;
  }
  bmode = sawf ? 2 : (sawbig ? 1 : 0);
}

__device__ inline int decode_key(const void* rel_raw, const void* ist_raw,
                                 int rel64, int bmode, int i) {
  const int* r32 = (const int*)rel_raw;
  int r = rel64 ? r32[2 * i] : r32[i];
  int truth;
  if (bmode == 1)      truth = (((const unsigned char*)ist_raw)[i] != 0);
  else if (bmode == 2) truth = (((const float*)ist_raw)[i] != 0.0f);
  else                 truth = (((const int*)ist_raw)[i] != 0);
  return truth ? r : -1;
}

__device__ inline bf16x8 cvt8(const float4& a, const float4& b) {
  bf16x8 v;
  v[0] = (__bf16)a.x; v[1] = (__bf16)a.y; v[2] = (__bf16)a.z; v[3] = (__bf16)a.w;
  v[4] = (__bf16)b.x; v[5] = (__bf16)b.y; v[6] = (__bf16)b.z; v[7] = (__bf16)b.w;
  return v;
}

// ---------------- prep: f32->bf16 convert + zero accumulators + decode keys -
__global__ void prep_kernel(const float* __restrict__ emb,
                            const void* __restrict__ rel_raw,
                            const void* __restrict__ ist_raw,
                            __bf16* __restrict__ embB,
                            float* __restrict__ sum_exp,
                            float* __restrict__ numer,
                            int* __restrict__ key) {
  int tid = blockIdx.x * 256 + threadIdx.x;
  size_t base = (size_t)tid * 8;
  if (base < (size_t)NB * ND) {
    float4 a = *(const float4*)(emb + base);
    float4 b = *(const float4*)(emb + base + 4);
    *(bf16x8*)(embB + base) = cvt8(a, b);
  }
  if (tid < NB) { sum_exp[tid] = 0.f; numer[tid] = 0.f; }
  __shared__ int s_rel64, s_bmode;
  if (blockIdx.x < 32) {                 // block-uniform branch
    if (threadIdx.x == 0) {
      int a, b; detect_formats(rel_raw, ist_raw, a, b);
      s_rel64 = a; s_bmode = b;
    }
    __syncthreads();
    int i = blockIdx.x * 256 + threadIdx.x;   // < 8192
    key[i] = decode_key(rel_raw, ist_raw, s_rel64, s_bmode, i);
  }
}

// small-ws fallback prep (no bf16 buffer)
__global__ void prep_small_kernel(const void* __restrict__ rel_raw,
                                  const void* __restrict__ ist_raw,
                                  float* __restrict__ sum_exp,
                                  float* __restrict__ numer,
                                  int* __restrict__ key) {
  int i = blockIdx.x * 256 + threadIdx.x;     // 32 blocks -> 8192
  sum_exp[i] = 0.f; numer[i] = 0.f;
  __shared__ int s_rel64, s_bmode;
  if (threadIdx.x == 0) {
    int a, b; detect_formats(rel_raw, ist_raw, a, b);
    s_rel64 = a; s_bmode = b;
  }
  __syncthreads();
  key[i] = decode_key(rel_raw, ist_raw, s_rel64, s_bmode, i);
}

// ---------------- fused symmetric GEMM (E E^T) + exp + masked sums ---------
// Upper-triangular tiling: only tiles with bx >= by are computed (2080 of
// 4096).  Diagonal tiles (bx==by) contribute row sums only (full 128x128
// minus diagonal).  Off-diagonal tiles contribute BOTH row sums (sim[i][j])
// and col sums (sim[j][i] == sim[i][j]) -- halving MFMA work.
// 128x128 tile, BK=64, 4 waves 2x2, each wave 64x64 = 4x4 frags of
// 16x16x32 bf16 MFMA.
template <bool F32STAGE>
__global__ __launch_bounds__(256, 4)
void gemm_fused_kernel(const __bf16* __restrict__ embB,
                       const float* __restrict__ embF,
                       const int* __restrict__ key,
                       float* __restrict__ sum_exp,
                       float* __restrict__ numer) {
  __shared__ __bf16 sA[128 * 64];
  __shared__ __bf16 sB[128 * 64];
  __shared__ int keyR[128], keyC[128];

  // triangular decode: t -> (bx >= by)
  const int t = blockIdx.x;
  int r = (int)((sqrtf(8.f * (float)t + 1.f) - 1.f) * 0.5f);
  while ((r + 1) * (r + 2) / 2 <= t) ++r;
  while (r * (r + 1) / 2 > t) --r;
  const int bx = r;                 // tile col
  const int by = t - r * (r + 1) / 2;   // tile row, by <= bx
  const bool diag = (bx == by);

  const int tid = threadIdx.x;
  const int wid = tid >> 6;
  const int l   = tid & 63;
  const int wr  = wid >> 1;     // wave row (0..1)
  const int wc  = wid & 1;      // wave col (0..1)
  const int rowBase = by * 128;
  const int colBase = bx * 128;

  if (tid < 128) keyR[tid] = key[rowBase + tid];
  else           keyC[tid - 128] = key[colBase + tid - 128];

  f32x4 acc[4][4] = {};

  for (int k0 = 0; k0 < ND; k0 += 64) {
    __syncthreads();   // previous iter's LDS reads done
    if constexpr (!F32STAGE) {
#pragma unroll
      for (int c = 0; c < 4; ++c) {
        int seg = wid * 4 + c;            // 0..15, wave-uniform
        int row = seg * 8 + (l >> 3);     // 0..127
        int ko  = (l & 7) * 8;
        const __bf16* ga = embB + (size_t)(rowBase + row) * ND + k0 + ko;
        const __bf16* gb = embB + (size_t)(colBase + row) * ND + k0 + ko;
        __builtin_amdgcn_global_load_lds(
            (const __attribute__((address_space(1))) void*)ga,
            (__attribute__((address_space(3))) void*)&sA[seg * 512], 16, 0, 0);
        __builtin_amdgcn_global_load_lds(
            (const __attribute__((address_space(1))) void*)gb,
            (__attribute__((address_space(3))) void*)&sB[seg * 512], 16, 0, 0);
      }
    } else {
#pragma unroll
      for (int c = 0; c < 4; ++c) {
        int chunk = tid + c * 256;        // 0..1023
        int row = chunk >> 3;
        int ko  = (chunk & 7) * 8;
        const float* gfa = embF + (size_t)(rowBase + row) * ND + k0 + ko;
        const float* gfb = embF + (size_t)(colBase + row) * ND + k0 + ko;
        float4 a0 = *(const float4*)gfa;
        float4 a1 = *(const float4*)(gfa + 4);
        float4 b0 = *(const float4*)gfb;
        float4 b1 = *(const float4*)(gfb + 4);
        *(bf16x8*)&sA[row * 64 + ko] = cvt8(a0, a1);
        *(bf16x8*)&sB[row * 64 + ko] = cvt8(b0, b1);
      }
    }
    __syncthreads();

#pragma unroll
    for (int kk = 0; kk < 2; ++kk) {
      bf16x8 af[4], bfr[4];
#pragma unroll
      for (int m = 0; m < 4; ++m)
        af[m] = *(const bf16x8*)&sA[(wr * 64 + m * 16 + (l & 15)) * 64 + kk * 32 + (l >> 4) * 8];
#pragma unroll
      for (int n = 0; n < 4; ++n)
        bfr[n] = *(const bf16x8*)&sB[(wc * 64 + n * 16 + (l & 15)) * 64 + kk * 32 + (l >> 4) * 8];
#pragma unroll
      for (int m = 0; m < 4; ++m)
#pragma unroll
        for (int n = 0; n < 4; ++n)
          acc[m][n] = __builtin_amdgcn_mfma_f32_16x16x32_bf16(af[m], bfr[n], acc[m][n], 0, 0, 0);
    }
  }

  // epilogue: C/D layout col = lane&15, row = (lane>>4)*4 + reg
  float cse[4] = {0.f, 0.f, 0.f, 0.f};   // per-col partial (off-diag only)
  float cnu[4] = {0.f, 0.f, 0.f, 0.f};
#pragma unroll
  for (int m = 0; m < 4; ++m) {
#pragma unroll
    for (int r4 = 0; r4 < 4; ++r4) {
      int li = wr * 64 + m * 16 + (l >> 4) * 4 + r4;
      int gi = rowBase + li;
      int krow = keyR[li];
      float se = 0.f, nu = 0.f;
#pragma unroll
      for (int n = 0; n < 4; ++n) {
        int lj = wc * 64 + n * 16 + (l & 15);
        int gj = colBase + lj;
        float e = __expf(acc[m][n][r4] * SCALE);
        if (gi == gj) e = 0.f;          // only possible on diagonal tiles
        bool match = (krow >= 0) && (krow == keyC[lj]);
        se += e;
        if (match) nu += e;
        if (!diag) {
          cse[n] += e;
          if (match) cnu[n] += e;
        }
      }
      // row-sum reduce across the 16 cols held by this lane group
#pragma unroll
      for (int off = 8; off; off >>= 1) {
        se += __shfl_xor(se, off, 16);
        nu += __shfl_xor(nu, off, 16);
      }
      if ((l & 15) == 0) {
        atomicAdd(&sum_exp[gi], se);
        if (nu != 0.f) atomicAdd(&numer[gi], nu);
      }
    }
  }
  if (!diag) {
    // col-sum reduce: combine the 4 row-groups (l>>4) holding the same col
#pragma unroll
    for (int n = 0; n < 4; ++n) {
      cse[n] += __shfl_xor(cse[n], 16);
      cse[n] += __shfl_xor(cse[n], 32);
      cnu[n] += __shfl_xor(cnu[n], 16);
      cnu[n] += __shfl_xor(cnu[n], 32);
    }
    if (l < 16) {
#pragma unroll
      for (int n = 0; n < 4; ++n) {
        int gj = colBase + wc * 64 + n * 16 + l;
        atomicAdd(&sum_exp[gj], cse[n]);
        if (cnu[n] != 0.f) atomicAdd(&numer[gj], cnu[n]);
      }
    }
  }
}

// ---------------- finalize: histogram -> has_pos, losses, reductions -------
__global__ void finalize_kernel(const float* __restrict__ sum_exp,
                                const float* __restrict__ numer,
                                const int* __restrict__ key,
                                float* __restrict__ out) {
  __shared__ int cnt[128];
  __shared__ float wsum[16];
  __shared__ int wcnt[16];
  int tid = threadIdx.x;      // 1024 threads
  if (tid < 128) cnt[tid] = 0;
  __syncthreads();
  for (int i = tid; i < NB; i += 1024) {
    int k = key[i];
    if (k >= 0) atomicAdd(&cnt[k], 1);
  }
  __syncthreads();
  float ls = 0.f; int np = 0;
  for (int i = tid; i < NB; i += 1024) {
    int k = key[i];
    if (k >= 0 && cnt[k] >= 2) {
      np++;
      ls += logf(sum_exp[i] + 1e-8f) - logf(numer[i]);
    }
  }
  for (int off = 32; off; off >>= 1) {
    ls += __shfl_down(ls, off, 64);
    np += __shfl_down(np, off, 64);
  }
  int w = tid >> 6;
  if ((tid & 63) == 0) { wsum[w] = ls; wcnt[w] = np; }
  __syncthreads();
  if (tid == 0) {
    float s = 0.f; int n = 0;
    for (int i = 0; i < 16; ++i) { s += wsum[i]; n += wcnt[i]; }
    out[0] = (n > 0) ? (s / (float)n) : 0.f;
    out[1] = (float)n;
  }
}

// ---------------------------------------------------------------------------
#define NTILES 64
#define NTRI (NTILES * (NTILES + 1) / 2)   // 2080

extern "C" void kernel_launch(void* const* d_in, const int* in_sizes, int n_in,
                              void* d_out, int out_size, void* d_ws, size_t ws_size,
                              hipStream_t stream) {
  const float* emb = (const float*)d_in[0];
  const void* rel  = d_in[1];
  const void* ist  = d_in[2];
  float* out = (float*)d_out;

  const size_t embBytes = (size_t)NB * ND * sizeof(__bf16);   // 16 MiB
  const size_t smallBytes = (size_t)NB * 4 * 3;               // 96 KiB

  char* ws = (char*)d_ws;
  if (ws_size >= embBytes + smallBytes) {
    __bf16* embB   = (__bf16*)ws;
    float* sum_exp = (float*)(ws + embBytes);
    float* numer   = sum_exp + NB;
    int*   key     = (int*)(numer + NB);
    prep_kernel<<<4096, 256, 0, stream>>>(emb, rel, ist, embB, sum_exp, numer, key);
    gemm_fused_kernel<false><<<NTRI, 256, 0, stream>>>(embB, nullptr, key, sum_exp, numer);
    finalize_kernel<<<1, 1024, 0, stream>>>(sum_exp, numer, key, out);
  } else {
    float* sum_exp = (float*)ws;
    float* numer   = sum_exp + NB;
    int*   key     = (int*)(numer + NB);
    prep_small_kernel<<<32, 256, 0, stream>>>(rel, ist, sum_exp, numer, key);
    gemm_fused_kernel<true><<<NTRI, 256, 0, stream>>>(nullptr, emb, key, sum_exp, numer);
    finalize_kernel<<<1, 1024, 0, stream>>>(sum_exp, numer, key, out);
  }
}